// Round 1
// baseline (884.729 us; speedup 1.0000x reference)
//
#include <hip/hip_runtime.h>
#include <hip/hip_bf16.h>

#define GROWS 32

// ---------------- degree / norm ----------------

__global__ void k_init_deg(int* __restrict__ deg, int n) {
    int i = blockIdx.x * blockDim.x + threadIdx.x;
    if (i < n) deg[i] = 1;  // self-loop contributes 1
}

__global__ void k_count_deg(const int* __restrict__ dst, int* __restrict__ deg, int e) {
    int i = blockIdx.x * blockDim.x + threadIdx.x;
    int stride = gridDim.x * blockDim.x;
    for (; i < e; i += stride) atomicAdd(&deg[dst[i]], 1);
}

__global__ void k_dinv(const int* __restrict__ deg, float* __restrict__ dinv, int n) {
    int i = blockIdx.x * blockDim.x + threadIdx.x;
    if (i < n) dinv[i] = rsqrtf((float)deg[i]);
}

// ---------------- layer 1 GEMM: h1 = x @ W1 ; agg1 = dinv^2 * h1 (self-loop init) ----------------

__global__ __launch_bounds__(256) void k_gemm1(
    const float* __restrict__ x, const float* __restrict__ W,
    const float* __restrict__ dinv, float* __restrict__ h1,
    float* __restrict__ agg1, int n) {
    __shared__ float Wl[128 * 128];   // 64 KB
    __shared__ float xs[GROWS * 128]; // 16 KB
    int t = threadIdx.x;

    // stage W1 (16384 floats = 4096 float4; 16 per thread), coalesced
    const float4* Wg = (const float4*)W;
    float4* Wl4 = (float4*)Wl;
#pragma unroll
    for (int i = 0; i < 16; ++i) Wl4[t + 256 * i] = Wg[t + 256 * i];

    long long row0 = (long long)blockIdx.x * GROWS;
    int rows = (int)(((long long)n - row0 < GROWS) ? ((long long)n - row0) : GROWS);

    // stage x tile (1024 float4; 4 per thread), zero tail rows
    const float4* xg = (const float4*)(x + row0 * 128);
    float4* xs4 = (float4*)xs;
#pragma unroll
    for (int i = 0; i < 4; ++i) {
        int idx = t + 256 * i;          // float4 index; row = idx/32
        if ((idx >> 5) < rows) xs4[idx] = xg[idx];
        else                   xs4[idx] = make_float4(0.f, 0.f, 0.f, 0.f);
    }
    __syncthreads();

    int tx = t & 127;   // output column
    int ty = t >> 7;    // 0..1, row parity
    float acc[16];
#pragma unroll
    for (int m = 0; m < 16; ++m) acc[m] = 0.f;

    for (int k = 0; k < 128; ++k) {
        float w = Wl[k * 128 + tx];           // conflict-free (2 lanes/bank)
#pragma unroll
        for (int m = 0; m < 16; ++m)
            acc[m] += xs[(2 * m + ty) * 128 + k] * w;  // broadcast reads
    }

#pragma unroll
    for (int m = 0; m < 16; ++m) {
        int r = 2 * m + ty;
        if (r < rows) {
            long long gi = (row0 + r) * 128 + tx;
            float v = acc[m];
            h1[gi] = v;
            float di = dinv[row0 + r];
            agg1[gi] = di * di * v;   // self-loop contribution
        }
    }
}

// ---------------- layer 1 edge aggregation (heavy kernel) ----------------
// one wave per edge: 64 lanes x float2 = 128 floats

__global__ __launch_bounds__(256) void k_edge_agg1(
    const int* __restrict__ src, const int* __restrict__ dst,
    const float* __restrict__ dinv, const float* __restrict__ h1,
    float* __restrict__ agg1, int e) {
    int wid = blockIdx.x * (blockDim.x >> 6) + (threadIdx.x >> 6);
    int lane = threadIdx.x & 63;
    int nw = gridDim.x * (blockDim.x >> 6);
    for (int i = wid; i < e; i += nw) {
        int ss = src[i];
        int dd = dst[i];
        float norm = dinv[ss] * dinv[dd];
        float2 v = ((const float2*)(h1 + (size_t)ss * 128))[lane];
        float* ap = agg1 + (size_t)dd * 128 + lane * 2;
        atomicAdd(ap,     v.x * norm);
        atomicAdd(ap + 1, v.y * norm);
    }
}

// ---------------- fused: z = relu(agg1+b1); s = z @ W2; out init = b2 + dinv^2*s ----------------
// one wave per node

__global__ __launch_bounds__(256) void k_sdot(
    const float* __restrict__ agg1, const float* __restrict__ b1,
    const float* __restrict__ W2, const float* __restrict__ b2,
    const float* __restrict__ dinv, float* __restrict__ s,
    float* __restrict__ out, int n) {
    int wid = blockIdx.x * (blockDim.x >> 6) + (threadIdx.x >> 6);
    int lane = threadIdx.x & 63;
    int nw = gridDim.x * (blockDim.x >> 6);
    for (int i = wid; i < n; i += nw) {
        float2 a  = ((const float2*)(agg1 + (size_t)i * 128))[lane];
        float2 bb = ((const float2*)b1)[lane];
        float2 ww = ((const float2*)W2)[lane];
        float p = fmaxf(a.x + bb.x, 0.f) * ww.x + fmaxf(a.y + bb.y, 0.f) * ww.y;
#pragma unroll
        for (int off = 32; off > 0; off >>= 1)
            p += __shfl_xor(p, off, 64);
        if (lane == 0) {
            float di = dinv[i];
            s[i] = p;
            out[i] = b2[0] + di * di * p;  // bias + self-loop
        }
    }
}

// ---------------- layer 2 edge aggregation (scalar) ----------------

__global__ void k_edge2(const int* __restrict__ src, const int* __restrict__ dst,
                        const float* __restrict__ dinv, const float* __restrict__ s,
                        float* __restrict__ out, int e) {
    int i = blockIdx.x * blockDim.x + threadIdx.x;
    int stride = gridDim.x * blockDim.x;
    for (; i < e; i += stride) {
        int ss = src[i];
        int dd = dst[i];
        atomicAdd(&out[dd], dinv[ss] * dinv[dd] * s[ss]);
    }
}

// ---------------- launch ----------------

extern "C" void kernel_launch(void* const* d_in, const int* in_sizes, int n_in,
                              void* d_out, int out_size, void* d_ws, size_t ws_size,
                              hipStream_t stream) {
    const float* x  = (const float*)d_in[0];
    const int*   ei = (const int*)d_in[1];   // [2,E] int32 (JAX x64 disabled)
    const float* W1 = (const float*)d_in[2];
    const float* b1 = (const float*)d_in[3];
    const float* W2 = (const float*)d_in[4];
    const float* b2 = (const float*)d_in[5];
    float* out = (float*)d_out;

    int n = in_sizes[0] / 128;
    int e = in_sizes[1] / 2;
    const int* srcp = ei;
    const int* dstp = ei + e;

    char* ws = (char*)d_ws;
    size_t off = 0;
    auto take = [&](size_t bytes) -> char* {
        char* p = ws + off;
        off += (bytes + 255) & ~(size_t)255;
        return p;
    };
    int*   deg  = (int*)take((size_t)n * 4);
    float* dinv = (float*)take((size_t)n * 4);
    float* s    = (float*)take((size_t)n * 4);
    float* h1   = (float*)take((size_t)n * 128 * 4);
    float* agg1 = (float*)take((size_t)n * 128 * 4);
    (void)ws_size;

    int ngrid = (n + 255) / 256;
    int egrid = (e + 255) / 256; if (egrid > 2048) egrid = 2048;

    hipLaunchKernelGGL(k_init_deg,  dim3(ngrid), dim3(256), 0, stream, deg, n);
    hipLaunchKernelGGL(k_count_deg, dim3(egrid), dim3(256), 0, stream, dstp, deg, e);
    hipLaunchKernelGGL(k_dinv,      dim3(ngrid), dim3(256), 0, stream, deg, dinv, n);
    hipLaunchKernelGGL(k_gemm1, dim3((n + GROWS - 1) / GROWS), dim3(256), 0, stream,
                       x, W1, dinv, h1, agg1, n);
    hipLaunchKernelGGL(k_edge_agg1, dim3(2048), dim3(256), 0, stream,
                       srcp, dstp, dinv, h1, agg1, e);
    hipLaunchKernelGGL(k_sdot, dim3(2048), dim3(256), 0, stream,
                       agg1, b1, W2, b2, dinv, s, out, n);
    hipLaunchKernelGGL(k_edge2, dim3(egrid), dim3(256), 0, stream,
                       srcp, dstp, dinv, s, out, e);
}

// Round 3
// 390.647 us; speedup vs baseline: 2.2648x; 2.2648x over previous
//
#include <hip/hip_runtime.h>
#include <hip/hip_bf16.h>

// ---------------- CSR build ----------------

__global__ void k_count_deg(const int* __restrict__ dst, int* __restrict__ deg, int e) {
    int i = blockIdx.x * blockDim.x + threadIdx.x;
    int stride = gridDim.x * blockDim.x;
    for (; i < e; i += stride) atomicAdd(&deg[dst[i]], 1);
}

// single-block exclusive scan of deg -> rowptr; also dinv = rsqrt(deg+1)
__global__ __launch_bounds__(1024) void k_scan(const int* __restrict__ deg,
                                               int* __restrict__ rowptr,
                                               float* __restrict__ dinv, int n) {
    __shared__ int sm[1024];
    int t = threadIdx.x;
    const int C = (n + 1023) / 1024;
    int base = t * C;
    int cnt = n - base; if (cnt < 0) cnt = 0; if (cnt > C) cnt = C;
    int tot = 0;
    for (int j = 0; j < cnt; ++j) {
        int d = deg[base + j];
        tot += d;
        dinv[base + j] = rsqrtf((float)(d + 1));   // +1 self-loop
    }
    sm[t] = tot;
    __syncthreads();
    for (int d = 1; d < 1024; d <<= 1) {           // Hillis-Steele inclusive
        int v = (t >= d) ? sm[t - d] : 0;
        __syncthreads();
        sm[t] += v;
        __syncthreads();
    }
    int run = sm[t] - tot;                          // exclusive prefix
    for (int j = 0; j < cnt; ++j) {
        rowptr[base + j] = run;
        run += deg[base + j];
    }
    if (t == 1023) rowptr[n] = sm[1023];
}

__global__ void k_scatter(const int* __restrict__ src, const int* __restrict__ dst,
                          const int* __restrict__ rowptr, int* __restrict__ cursor,
                          int* __restrict__ eidx, int e) {
    int i = blockIdx.x * blockDim.x + threadIdx.x;
    int stride = gridDim.x * blockDim.x;
    for (; i < e; i += stride) {
        int d = dst[i];
        int pos = rowptr[d] + atomicAdd(&cursor[d], 1);
        eidx[pos] = src[i];
    }
}

// ---------------- layer 1 GEMM: h1 = x @ W1 ----------------
// 64 rows/block, 512 threads, 4x4 register tiles, k-chunked by 4.

#define GR 64

__global__ __launch_bounds__(512) void k_gemm1(const float* __restrict__ x,
                                               const float* __restrict__ W,
                                               float* __restrict__ h1, int n) {
    __shared__ float Wl[128 * 128];   // 64 KB, [k][c]
    __shared__ float xs[GR * 128];    // 32 KB, [r][k]
    int t = threadIdx.x;

    const float4* Wg = (const float4*)W;
    float4* Wl4 = (float4*)Wl;
#pragma unroll
    for (int ii = 0; ii < 8; ++ii) Wl4[t + 512 * ii] = Wg[t + 512 * ii];

    long long row0 = (long long)blockIdx.x * GR;
    int rows = (int)(((long long)n - row0 < GR) ? ((long long)n - row0) : GR);
    const float4* xg = (const float4*)(x + row0 * 128);
    float4* xs4 = (float4*)xs;
#pragma unroll
    for (int ii = 0; ii < 4; ++ii) {
        int idx = t + 512 * ii;        // float4 idx; row = idx>>5
        xs4[idx] = ((idx >> 5) < rows) ? xg[idx] : make_float4(0.f, 0.f, 0.f, 0.f);
    }
    __syncthreads();

    int tx = t & 31, ty = t >> 5;      // 32 col-groups x 16 row-groups
    int c0 = tx * 4, r0 = ty * 4;
    float acc[4][4];
#pragma unroll
    for (int q = 0; q < 4; ++q)
#pragma unroll
        for (int j = 0; j < 4; ++j) acc[q][j] = 0.f;

    for (int k = 0; k < 128; k += 4) {
        float4 xv[4], wv[4];
#pragma unroll
        for (int q = 0; q < 4; ++q) xv[q] = *(const float4*)&xs[(r0 + q) * 128 + k];
#pragma unroll
        for (int kk = 0; kk < 4; ++kk) wv[kk] = *(const float4*)&Wl[(k + kk) * 128 + c0];
#pragma unroll
        for (int q = 0; q < 4; ++q) {
            const float* xq = (const float*)&xv[q];
#pragma unroll
            for (int kk = 0; kk < 4; ++kk) {
                const float* wk = (const float*)&wv[kk];
                acc[q][0] += xq[kk] * wk[0];
                acc[q][1] += xq[kk] * wk[1];
                acc[q][2] += xq[kk] * wk[2];
                acc[q][3] += xq[kk] * wk[3];
            }
        }
    }

#pragma unroll
    for (int q = 0; q < 4; ++q) {
        if (r0 + q < rows) {
            float4 o = make_float4(acc[q][0], acc[q][1], acc[q][2], acc[q][3]);
            *(float4*)&h1[(row0 + r0 + q) * 128 + c0] = o;
        }
    }
}

// ---------------- fused layer-1 aggregation + bias + relu + W2 dot ----------------
// one wave per node; CSR gather of h1 rows; no atomics, no agg1 in memory.

__global__ __launch_bounds__(256) void k_agg_s(
    const int* __restrict__ rowptr, const int* __restrict__ eidx,
    const float* __restrict__ dinv, const float* __restrict__ h1,
    const float* __restrict__ b1, const float* __restrict__ W2,
    float* __restrict__ s, int n) {
    int lane = threadIdx.x & 63;
    int wid = blockIdx.x * (blockDim.x >> 6) + (threadIdx.x >> 6);
    wid = __builtin_amdgcn_readfirstlane(wid);   // force SGPR -> s_load addressing
    int nw = gridDim.x * (blockDim.x >> 6);
    float2 bb = ((const float2*)b1)[lane];
    float2 ww = ((const float2*)W2)[lane];
    for (int i = wid; i < n; i += nw) {
        float di = dinv[i];
        float2 acc = ((const float2*)(h1 + (size_t)i * 128))[lane];
        float self = di * di;
        acc.x *= self; acc.y *= self;
        int j = rowptr[i], end = rowptr[i + 1];
        for (; j + 4 <= end; j += 4) {
            int s0 = eidx[j], s1 = eidx[j + 1], s2 = eidx[j + 2], s3 = eidx[j + 3];
            float n0 = dinv[s0] * di, n1 = dinv[s1] * di;
            float n2 = dinv[s2] * di, n3 = dinv[s3] * di;
            float2 v0 = ((const float2*)(h1 + (size_t)s0 * 128))[lane];
            float2 v1 = ((const float2*)(h1 + (size_t)s1 * 128))[lane];
            float2 v2 = ((const float2*)(h1 + (size_t)s2 * 128))[lane];
            float2 v3 = ((const float2*)(h1 + (size_t)s3 * 128))[lane];
            acc.x += v0.x * n0; acc.y += v0.y * n0;
            acc.x += v1.x * n1; acc.y += v1.y * n1;
            acc.x += v2.x * n2; acc.y += v2.y * n2;
            acc.x += v3.x * n3; acc.y += v3.y * n3;
        }
        for (; j < end; ++j) {
            int ss = eidx[j];
            float nn = dinv[ss] * di;
            float2 v = ((const float2*)(h1 + (size_t)ss * 128))[lane];
            acc.x += v.x * nn; acc.y += v.y * nn;
        }
        float p = fmaxf(acc.x + bb.x, 0.f) * ww.x + fmaxf(acc.y + bb.y, 0.f) * ww.y;
#pragma unroll
        for (int off = 32; off > 0; off >>= 1)
            p += __shfl_xor(p, off, 64);
        if (lane == 0) s[i] = p;
    }
}

// ---------------- layer 2: per-thread CSR gather of s ----------------

__global__ void k_out2(const int* __restrict__ rowptr, const int* __restrict__ eidx,
                       const float* __restrict__ dinv, const float* __restrict__ s,
                       const float* __restrict__ b2, float* __restrict__ out, int n) {
    int i = blockIdx.x * blockDim.x + threadIdx.x;
    if (i >= n) return;
    float di = dinv[i];
    float acc = di * s[i];                 // self-loop (one di applied at the end)
    int j = rowptr[i], end = rowptr[i + 1];
    for (; j < end; ++j) {
        int ss = eidx[j];
        acc += dinv[ss] * s[ss];
    }
    out[i] = b2[0] + di * acc;
}

// ---------------- launch ----------------

extern "C" void kernel_launch(void* const* d_in, const int* in_sizes, int n_in,
                              void* d_out, int out_size, void* d_ws, size_t ws_size,
                              hipStream_t stream) {
    const float* x  = (const float*)d_in[0];
    const int*   ei = (const int*)d_in[1];   // [2,E] int32
    const float* W1 = (const float*)d_in[2];
    const float* b1 = (const float*)d_in[3];
    const float* W2 = (const float*)d_in[4];
    const float* b2 = (const float*)d_in[5];
    float* out = (float*)d_out;

    int n = in_sizes[0] / 128;
    int e = in_sizes[1] / 2;
    const int* srcp = ei;
    const int* dstp = ei + e;

    char* ws = (char*)d_ws;
    size_t off = 0;
    auto take = [&](size_t bytes) -> char* {
        char* p = ws + off;
        off += (bytes + 255) & ~(size_t)255;
        return p;
    };
    int*   deg    = (int*)take((size_t)n * 4);
    int*   cursor = (int*)take((size_t)n * 4);   // must stay adjacent to deg (joint memset)
    int*   rowptr = (int*)take((size_t)(n + 1) * 4);
    float* dinv   = (float*)take((size_t)n * 4);
    float* s      = (float*)take((size_t)n * 4);
    int*   eidx   = (int*)take((size_t)e * 4);
    float* h1     = (float*)take((size_t)n * 128 * 4);
    (void)ws_size;

    int egrid = (e + 255) / 256; if (egrid > 2048) egrid = 2048;
    int ngrid = (n + 255) / 256;

    // deg and cursor are contiguous (each 256B-aligned, n*4 rounded): zero both.
    hipMemsetAsync(deg, 0, (((size_t)n * 4 + 255) & ~(size_t)255) + (size_t)n * 4, stream);

    hipLaunchKernelGGL(k_count_deg, dim3(egrid), dim3(256), 0, stream, dstp, deg, e);
    hipLaunchKernelGGL(k_scan, dim3(1), dim3(1024), 0, stream, deg, rowptr, dinv, n);
    hipLaunchKernelGGL(k_scatter, dim3(egrid), dim3(256), 0, stream,
                       srcp, dstp, rowptr, cursor, eidx, e);
    hipLaunchKernelGGL(k_gemm1, dim3((n + GR - 1) / GR), dim3(512), 0, stream,
                       x, W1, h1, n);
    hipLaunchKernelGGL(k_agg_s, dim3(2048), dim3(256), 0, stream,
                       rowptr, eidx, dinv, h1, b1, W2, s, n);
    hipLaunchKernelGGL(k_out2, dim3(ngrid), dim3(256), 0, stream,
                       rowptr, eidx, dinv, s, b2, out, n);
}

// Round 5
// 268.714 us; speedup vs baseline: 3.2925x; 1.4538x over previous
//
#include <hip/hip_runtime.h>
#include <hip/hip_bf16.h>

// ---------------- CSR build ----------------

__global__ void k_count_deg(const int* __restrict__ dst, int* __restrict__ deg, int e) {
    int i = blockIdx.x * blockDim.x + threadIdx.x;
    int stride = gridDim.x * blockDim.x;
    for (; i < e; i += stride) atomicAdd(&deg[dst[i]], 1);
}

// ---- hierarchical scan: deg -> rowptr (exclusive), plus dinv = rsqrt(deg+1) ----

// pass 1: per-block (512 elems) sums + dinv
__global__ __launch_bounds__(512) void k_scan1(const int* __restrict__ deg,
                                               float* __restrict__ dinv,
                                               int* __restrict__ bsum, int n) {
    int t = threadIdx.x;
    int i = blockIdx.x * 512 + t;
    int d = (i < n) ? deg[i] : 0;
    if (i < n) dinv[i] = rsqrtf((float)(d + 1));   // +1 self-loop
    int v = d;
#pragma unroll
    for (int off = 32; off > 0; off >>= 1) v += __shfl_xor(v, off, 64);
    __shared__ int wsum[8];
    if ((t & 63) == 0) wsum[t >> 6] = v;
    __syncthreads();
    if (t == 0) {
        int s = 0;
#pragma unroll
        for (int j = 0; j < 8; ++j) s += wsum[j];
        bsum[blockIdx.x] = s;
    }
}

// pass 2: single small block scans the block sums in-place (exclusive)
__global__ __launch_bounds__(256) void k_scan2(int* __restrict__ bsum, int nb) {
    __shared__ int sm[256];
    int t = threadIdx.x;
    int C = (nb + 255) / 256;
    int base = t * C;
    int tot = 0;
    for (int j = 0; j < C; ++j) { int k = base + j; if (k < nb) tot += bsum[k]; }
    sm[t] = tot;
    __syncthreads();
    for (int d = 1; d < 256; d <<= 1) {
        int v = (t >= d) ? sm[t - d] : 0;
        __syncthreads();
        sm[t] += v;
        __syncthreads();
    }
    int run = sm[t] - tot;   // exclusive over chunks
    for (int j = 0; j < C; ++j) {
        int k = base + j;
        if (k < nb) { int d0 = bsum[k]; bsum[k] = run; run += d0; }
    }
}

// pass 3: per-block exclusive scan + block offset -> rowptr
__global__ __launch_bounds__(512) void k_scan3(const int* __restrict__ deg,
                                               const int* __restrict__ bsum,
                                               int* __restrict__ rowptr, int n) {
    __shared__ int sm[512];
    int t = threadIdx.x;
    int i = blockIdx.x * 512 + t;
    int d = (i < n) ? deg[i] : 0;
    sm[t] = d;
    __syncthreads();
    for (int dd = 1; dd < 512; dd <<= 1) {
        int v = (t >= dd) ? sm[t - dd] : 0;
        __syncthreads();
        sm[t] += v;
        __syncthreads();
    }
    int excl = sm[t] - d;
    if (i < n) {
        int base = bsum[blockIdx.x];
        rowptr[i] = base + excl;
        if (i == n - 1) rowptr[n] = base + excl + d;
    }
}

__global__ void k_scatter(const int* __restrict__ src, const int* __restrict__ dst,
                          const int* __restrict__ rowptr, int* __restrict__ cursor,
                          int* __restrict__ eidx, int e) {
    int i = blockIdx.x * blockDim.x + threadIdx.x;
    int stride = gridDim.x * blockDim.x;
    for (; i < e; i += stride) {
        int d = dst[i];
        int pos = rowptr[d] + atomicAdd(&cursor[d], 1);
        eidx[pos] = src[i];
    }
}

// ---------------- layer 1 GEMM: h1 = x @ W1 ----------------
// 64 rows/block, 512 threads, 4x4 register tiles.
// W in LDS (64 KB -> 2 blocks/CU); x read from global (half-wave broadcast, L1).

#define GR 64

__global__ __launch_bounds__(512) void k_gemm1(const float* __restrict__ x,
                                               const float* __restrict__ W,
                                               float* __restrict__ h1, int n) {
    __shared__ float Wl[128 * 128];   // 64 KB, [k][c]
    int t = threadIdx.x;

    const float4* Wg = (const float4*)W;
    float4* Wl4 = (float4*)Wl;
#pragma unroll
    for (int ii = 0; ii < 8; ++ii) Wl4[t + 512 * ii] = Wg[t + 512 * ii];
    __syncthreads();

    long long row0 = (long long)blockIdx.x * GR;
    int rows = (int)(((long long)n - row0 < GR) ? ((long long)n - row0) : GR);

    int tx = t & 31, ty = t >> 5;      // 32 col-groups x 16 row-groups
    int c0 = tx * 4, r0 = ty * 4;

    // clamped per-q row pointers (tail rows point at row 0; result discarded)
    const float4* xr[4];
#pragma unroll
    for (int q = 0; q < 4; ++q) {
        int r = r0 + q; if (r >= rows) r = 0;
        xr[q] = (const float4*)(x + (row0 + r) * 128);
    }

    float acc[4][4];
#pragma unroll
    for (int q = 0; q < 4; ++q)
#pragma unroll
        for (int j = 0; j < 4; ++j) acc[q][j] = 0.f;

#pragma unroll 4
    for (int kc = 0; kc < 32; ++kc) {
        float4 xv[4];
#pragma unroll
        for (int q = 0; q < 4; ++q) xv[q] = xr[q][kc];
#pragma unroll
        for (int kk = 0; kk < 4; ++kk) {
            float4 wv = *(const float4*)&Wl[(kc * 4 + kk) * 128 + c0];
#pragma unroll
            for (int q = 0; q < 4; ++q) {
                float xq = ((const float*)&xv[q])[kk];
                acc[q][0] += xq * wv.x;
                acc[q][1] += xq * wv.y;
                acc[q][2] += xq * wv.z;
                acc[q][3] += xq * wv.w;
            }
        }
    }

#pragma unroll
    for (int q = 0; q < 4; ++q) {
        if (r0 + q < rows) {
            float4 o = make_float4(acc[q][0], acc[q][1], acc[q][2], acc[q][3]);
            *(float4*)&h1[(row0 + r0 + q) * 128 + c0] = o;
        }
    }
}

// ---------------- fused layer-1 aggregation + bias + relu + W2 dot ----------------
// one wave per node; CSR gather of h1 rows; no atomics, no agg1 in memory.

__global__ __launch_bounds__(256) void k_agg_s(
    const int* __restrict__ rowptr, const int* __restrict__ eidx,
    const float* __restrict__ dinv, const float* __restrict__ h1,
    const float* __restrict__ b1, const float* __restrict__ W2,
    float* __restrict__ s, int n) {
    int lane = threadIdx.x & 63;
    int wid = blockIdx.x * (blockDim.x >> 6) + (threadIdx.x >> 6);
    wid = __builtin_amdgcn_readfirstlane(wid);
    int nw = gridDim.x * (blockDim.x >> 6);
    float2 bb = ((const float2*)b1)[lane];
    float2 ww = ((const float2*)W2)[lane];
    for (int i = wid; i < n; i += nw) {
        float di = dinv[i];
        float2 acc = ((const float2*)(h1 + (size_t)i * 128))[lane];
        float self = di * di;
        acc.x *= self; acc.y *= self;
        int j = rowptr[i], end = rowptr[i + 1];
        for (; j + 4 <= end; j += 4) {
            int s0 = eidx[j], s1 = eidx[j + 1], s2 = eidx[j + 2], s3 = eidx[j + 3];
            float n0 = dinv[s0] * di, n1 = dinv[s1] * di;
            float n2 = dinv[s2] * di, n3 = dinv[s3] * di;
            float2 v0 = ((const float2*)(h1 + (size_t)s0 * 128))[lane];
            float2 v1 = ((const float2*)(h1 + (size_t)s1 * 128))[lane];
            float2 v2 = ((const float2*)(h1 + (size_t)s2 * 128))[lane];
            float2 v3 = ((const float2*)(h1 + (size_t)s3 * 128))[lane];
            acc.x += v0.x * n0; acc.y += v0.y * n0;
            acc.x += v1.x * n1; acc.y += v1.y * n1;
            acc.x += v2.x * n2; acc.y += v2.y * n2;
            acc.x += v3.x * n3; acc.y += v3.y * n3;
        }
        for (; j < end; ++j) {
            int ss = eidx[j];
            float nn = dinv[ss] * di;
            float2 v = ((const float2*)(h1 + (size_t)ss * 128))[lane];
            acc.x += v.x * nn; acc.y += v.y * nn;
        }
        float p = fmaxf(acc.x + bb.x, 0.f) * ww.x + fmaxf(acc.y + bb.y, 0.f) * ww.y;
#pragma unroll
        for (int off = 32; off > 0; off >>= 1)
            p += __shfl_xor(p, off, 64);
        if (lane == 0) s[i] = p;
    }
}

// ---------------- layer 2: per-thread CSR gather of s ----------------

__global__ void k_out2(const int* __restrict__ rowptr, const int* __restrict__ eidx,
                       const float* __restrict__ dinv, const float* __restrict__ s,
                       const float* __restrict__ b2, float* __restrict__ out, int n) {
    int i = blockIdx.x * blockDim.x + threadIdx.x;
    if (i >= n) return;
    float di = dinv[i];
    float acc = di * s[i];                 // self-loop
    int j = rowptr[i], end = rowptr[i + 1];
    for (; j < end; ++j) {
        int ss = eidx[j];
        acc += dinv[ss] * s[ss];
    }
    out[i] = b2[0] + di * acc;
}

// ---------------- launch ----------------

extern "C" void kernel_launch(void* const* d_in, const int* in_sizes, int n_in,
                              void* d_out, int out_size, void* d_ws, size_t ws_size,
                              hipStream_t stream) {
    const float* x  = (const float*)d_in[0];
    const int*   ei = (const int*)d_in[1];   // [2,E] int32
    const float* W1 = (const float*)d_in[2];
    const float* b1 = (const float*)d_in[3];
    const float* W2 = (const float*)d_in[4];
    const float* b2 = (const float*)d_in[5];
    float* out = (float*)d_out;

    int n = in_sizes[0] / 128;
    int e = in_sizes[1] / 2;
    const int* srcp = ei;
    const int* dstp = ei + e;

    char* ws = (char*)d_ws;
    size_t off = 0;
    auto take = [&](size_t bytes) -> char* {
        char* p = ws + off;
        off += (bytes + 255) & ~(size_t)255;
        return p;
    };
    int*   deg    = (int*)take((size_t)n * 4);
    int*   cursor = (int*)take((size_t)n * 4);   // adjacent to deg (joint memset)
    int*   rowptr = (int*)take((size_t)(n + 1) * 4);
    float* dinv   = (float*)take((size_t)n * 4);
    float* s      = (float*)take((size_t)n * 4);
    int*   eidx   = (int*)take((size_t)e * 4);
    int*   bsum   = (int*)take((size_t)4096 * 4);
    float* h1     = (float*)take((size_t)n * 128 * 4);
    (void)ws_size;

    int egrid = (e + 255) / 256; if (egrid > 2048) egrid = 2048;
    int ngrid = (n + 255) / 256;
    int nscan = (n + 511) / 512;   // 98 blocks

    // deg and cursor are contiguous: zero both in one memset.
    hipMemsetAsync(deg, 0, (((size_t)n * 4 + 255) & ~(size_t)255) + (size_t)n * 4, stream);

    hipLaunchKernelGGL(k_count_deg, dim3(egrid), dim3(256), 0, stream, dstp, deg, e);
    hipLaunchKernelGGL(k_scan1, dim3(nscan), dim3(512), 0, stream, deg, dinv, bsum, n);
    hipLaunchKernelGGL(k_scan2, dim3(1), dim3(256), 0, stream, bsum, nscan);
    hipLaunchKernelGGL(k_scan3, dim3(nscan), dim3(512), 0, stream, deg, bsum, rowptr, n);
    hipLaunchKernelGGL(k_scatter, dim3(egrid), dim3(256), 0, stream,
                       srcp, dstp, rowptr, cursor, eidx, e);
    hipLaunchKernelGGL(k_gemm1, dim3((n + GR - 1) / GR), dim3(512), 0, stream,
                       x, W1, h1, n);
    hipLaunchKernelGGL(k_agg_s, dim3(2048), dim3(256), 0, stream,
                       rowptr, eidx, dinv, h1, b1, W2, s, n);
    hipLaunchKernelGGL(k_out2, dim3(ngrid), dim3(256), 0, stream,
                       rowptr, eidx, dinv, s, b2, out, n);
}